// Round 3
// baseline (2678.056 us; speedup 1.0000x reference)
//
#include <hip/hip_runtime.h>
#include <cstddef>

// DecoderLayer: T=4, B=4, N=512, D=512, F=2048, H=8, head_dim=64
// I/O dtype: float32 (per reference). Spike intermediates in d_ws: bf16 (exact
// for {0,1,2}). GEMM accumulation + LIF recurrence in f64 to match an np
// float64 reference bit-for-bit on spike decisions.
#define T_STEPS 4
#define BN 2048                    /* B*N rows per time plane */
#define N_TOK 512
#define D_DIM 512
#define F_DIM 2048

#define MODE_SPK 0
#define MODE_SPK_ADD 1
#define MODE_OUT 2

__device__ __forceinline__ float bf2f(unsigned short u) {
  unsigned int x = ((unsigned int)u) << 16;
  float f;
  __builtin_memcpy(&f, &x, 4);
  return f;
}
__device__ __forceinline__ unsigned short f2bf(float f) {
  unsigned int x;
  __builtin_memcpy(&x, &f, 4);
  x += 0x7fffu + ((x >> 16) & 1u);  // round to nearest even
  return (unsigned short)(x >> 16);
}
__device__ __forceinline__ void unpack8(uint4 p, float* f) {
  f[0] = bf2f((unsigned short)(p.x & 0xffffu));
  f[1] = bf2f((unsigned short)(p.x >> 16));
  f[2] = bf2f((unsigned short)(p.y & 0xffffu));
  f[3] = bf2f((unsigned short)(p.y >> 16));
  f[4] = bf2f((unsigned short)(p.z & 0xffffu));
  f[5] = bf2f((unsigned short)(p.z >> 16));
  f[6] = bf2f((unsigned short)(p.w & 0xffffu));
  f[7] = bf2f((unsigned short)(p.w >> 16));
}

// ---------------------------------------------------------------------------
// Fused GEMM + LIF over T. For a 32-row x 64-col tile and all 4 time planes:
//   u[t] = (A1[t] + A2[t]) @ W + bias   (f64 accumulation; A2 optional)
// then LIF across t (f64 state) and writes per mode:
//   MODE_SPK:     bf16 spikes
//   MODE_SPK_ADD: bf16 (Sprev + spike)        (exact small ints)
//   MODE_OUT:     f32  (Xres + S12 + spike)   (final residual output)
// A1: f32 [T*BN,K] if a1bf==0, else bf16 spikes. W,bias: f32. Grid (N/64,BN/32).
// ---------------------------------------------------------------------------
__global__ __launch_bounds__(256) void gemm_lif(
    const void* __restrict__ A1v,
    const unsigned short* __restrict__ A2,     // nullable bf16 spike-sum
    const float* __restrict__ W,
    const float* __restrict__ bias,
    const unsigned short* Sprev,               // mode 1 (may alias outv)
    const float* __restrict__ Xres,            // mode 2
    const unsigned short* __restrict__ S12,    // mode 2
    void* outv,
    int N, int K, int mode, int a1bf) {
  __shared__ float Ax[T_STEPS][16][34];
  __shared__ float Sx[T_STEPS][16][34];
  __shared__ float Wt[16][68];

  const int tid = threadIdx.x;
  const int tx4 = (tid & 15) * 4;   // col offset in tile
  const int ty2 = (tid >> 4) * 2;   // row offset in tile
  const int n0 = blockIdx.x * 64;
  const int bn0 = blockIdx.y * 32;

  // staging: A -> (t, row, k-half of 8), W -> (k-row, col-quad)
  const int t_s = tid >> 6;
  const int rem = tid & 63;
  const int row_s = rem >> 1;
  const int kh_s = (rem & 1) * 8;
  const int wr = tid >> 4;
  const int wc = (tid & 15) * 4;

  if (A2 == nullptr) {  // zero the spike-part once; covered by first barrier
#pragma unroll
    for (int j = 0; j < 8; ++j) Sx[t_s][kh_s + j][row_s] = 0.f;
  }

  double acc[T_STEPS][2][4];
#pragma unroll
  for (int t = 0; t < T_STEPS; ++t)
#pragma unroll
    for (int i = 0; i < 2; ++i)
#pragma unroll
      for (int j = 0; j < 4; ++j) acc[t][i][j] = 0.0;

  for (int k0 = 0; k0 < K; k0 += 16) {
    size_t aoff = (size_t)(t_s * BN + bn0 + row_s) * K + (k0 + kh_s);
    if (a1bf) {
      uint4 p = *reinterpret_cast<const uint4*>((const unsigned short*)A1v + aoff);
      float f[8];
      unpack8(p, f);
#pragma unroll
      for (int j = 0; j < 8; ++j) Ax[t_s][kh_s + j][row_s] = f[j];
    } else {
      const float* A1 = (const float*)A1v;
      float4 a = *reinterpret_cast<const float4*>(A1 + aoff);
      float4 b = *reinterpret_cast<const float4*>(A1 + aoff + 4);
      Ax[t_s][kh_s + 0][row_s] = a.x; Ax[t_s][kh_s + 1][row_s] = a.y;
      Ax[t_s][kh_s + 2][row_s] = a.z; Ax[t_s][kh_s + 3][row_s] = a.w;
      Ax[t_s][kh_s + 4][row_s] = b.x; Ax[t_s][kh_s + 5][row_s] = b.y;
      Ax[t_s][kh_s + 6][row_s] = b.z; Ax[t_s][kh_s + 7][row_s] = b.w;
    }
    if (A2 != nullptr) {
      uint4 q = *reinterpret_cast<const uint4*>(A2 + aoff);
      float g[8];
      unpack8(q, g);
#pragma unroll
      for (int j = 0; j < 8; ++j) Sx[t_s][kh_s + j][row_s] = g[j];
    }
    {
      size_t woff = (size_t)(k0 + wr) * N + (n0 + wc);
      float4 w4 = *reinterpret_cast<const float4*>(W + woff);
      Wt[wr][wc + 0] = w4.x; Wt[wr][wc + 1] = w4.y;
      Wt[wr][wc + 2] = w4.z; Wt[wr][wc + 3] = w4.w;
    }
    __syncthreads();
#pragma unroll
    for (int kk = 0; kk < 16; ++kk) {
      double b0 = (double)Wt[kk][tx4 + 0];
      double b1 = (double)Wt[kk][tx4 + 1];
      double b2 = (double)Wt[kk][tx4 + 2];
      double b3 = (double)Wt[kk][tx4 + 3];
#pragma unroll
      for (int t = 0; t < T_STEPS; ++t) {
        double a0 = (double)Ax[t][kk][ty2 + 0] + (double)Sx[t][kk][ty2 + 0];
        double a1 = (double)Ax[t][kk][ty2 + 1] + (double)Sx[t][kk][ty2 + 1];
        acc[t][0][0] += a0 * b0; acc[t][0][1] += a0 * b1;
        acc[t][0][2] += a0 * b2; acc[t][0][3] += a0 * b3;
        acc[t][1][0] += a1 * b0; acc[t][1][1] += a1 * b1;
        acc[t][1][2] += a1 * b2; acc[t][1][3] += a1 * b3;
      }
    }
    __syncthreads();
  }

  double bd[4];
#pragma unroll
  for (int j = 0; j < 4; ++j) bd[j] = (double)bias[n0 + tx4 + j];

#pragma unroll
  for (int i = 0; i < 2; ++i) {
    const int bn = bn0 + ty2 + i;
    double v0 = 0.0, v1 = 0.0, v2 = 0.0, v3 = 0.0;
#pragma unroll
    for (int t = 0; t < T_STEPS; ++t) {
      size_t ridx = (size_t)(t * BN + bn) * N + (n0 + tx4);
      double u0 = acc[t][i][0] + bd[0];
      double u1 = acc[t][i][1] + bd[1];
      double u2 = acc[t][i][2] + bd[2];
      double u3 = acc[t][i][3] + bd[3];
      v0 = v0 + (u0 - v0) * 0.5;
      v1 = v1 + (u1 - v1) * 0.5;
      v2 = v2 + (u2 - v2) * 0.5;
      v3 = v3 + (u3 - v3) * 0.5;
      float s0 = (v0 >= 1.0) ? 1.0f : 0.0f;
      float s1 = (v1 >= 1.0) ? 1.0f : 0.0f;
      float s2 = (v2 >= 1.0) ? 1.0f : 0.0f;
      float s3 = (v3 >= 1.0) ? 1.0f : 0.0f;
      v0 = (v0 >= 1.0) ? 0.0 : v0;
      v1 = (v1 >= 1.0) ? 0.0 : v1;
      v2 = (v2 >= 1.0) ? 0.0 : v2;
      v3 = (v3 >= 1.0) ? 0.0 : v3;
      if (mode == MODE_SPK) {
        ushort4 o;
        o.x = f2bf(s0); o.y = f2bf(s1); o.z = f2bf(s2); o.w = f2bf(s3);
        *reinterpret_cast<ushort4*>((unsigned short*)outv + ridx) = o;
      } else if (mode == MODE_SPK_ADD) {
        ushort4 p = *reinterpret_cast<const ushort4*>(Sprev + ridx);
        ushort4 o;
        o.x = f2bf(s0 + bf2f(p.x)); o.y = f2bf(s1 + bf2f(p.y));
        o.z = f2bf(s2 + bf2f(p.z)); o.w = f2bf(s3 + bf2f(p.w));
        *reinterpret_cast<ushort4*>((unsigned short*)outv + ridx) = o;
      } else {
        float4 xr = *reinterpret_cast<const float4*>(Xres + ridx);
        ushort4 sp = *reinterpret_cast<const ushort4*>(S12 + ridx);
        float4 o;
        o.x = (float)((double)xr.x + (double)bf2f(sp.x) + (double)s0);
        o.y = (float)((double)xr.y + (double)bf2f(sp.y) + (double)s1);
        o.z = (float)((double)xr.z + (double)bf2f(sp.z) + (double)s2);
        o.w = (float)((double)xr.w + (double)bf2f(sp.w) + (double)s3);
        *reinterpret_cast<float4*>((float*)outv + ridx) = o;
      }
    }
  }
}

// ---------------------------------------------------------------------------
// Spiking attention, reassociated: u = 0.125 * q @ (k^T @ v) per (t,b,h).
// Spikes are 0/1 -> exact integer sums (< 2^24) in f32; identical to the
// reference's (q@k^T)@v order. bf16 spikes in, exact f32 u out. Grid 128.
// ---------------------------------------------------------------------------
__global__ __launch_bounds__(256) void attn_k(const unsigned short* __restrict__ Q,
                                              const unsigned short* __restrict__ K,
                                              const unsigned short* __restrict__ V,
                                              float* __restrict__ O) {
  const int blk = blockIdx.x;
  const int h = blk & 7;
  const int tb = blk >> 3;
  const size_t base = (size_t)tb * (N_TOK * D_DIM) + h * 64;
  const int tid = threadIdx.x;
  const int tx = tid & 15, ty = tid >> 4;

  __shared__ float Kt[64][65];
  __shared__ float Vt[64][65];
  __shared__ float St[64][65];

  float S[4][4] = {};
  for (int mc = 0; mc < N_TOK; mc += 64) {
#pragma unroll
    for (int rr = 0; rr < 4; ++rr) {
      int row = rr * 16 + ty;
      ushort4 k4 = *reinterpret_cast<const ushort4*>(K + base + (size_t)(mc + row) * D_DIM + tx * 4);
      ushort4 v4 = *reinterpret_cast<const ushort4*>(V + base + (size_t)(mc + row) * D_DIM + tx * 4);
      Kt[row][tx * 4 + 0] = bf2f(k4.x); Kt[row][tx * 4 + 1] = bf2f(k4.y);
      Kt[row][tx * 4 + 2] = bf2f(k4.z); Kt[row][tx * 4 + 3] = bf2f(k4.w);
      Vt[row][tx * 4 + 0] = bf2f(v4.x); Vt[row][tx * 4 + 1] = bf2f(v4.y);
      Vt[row][tx * 4 + 2] = bf2f(v4.z); Vt[row][tx * 4 + 3] = bf2f(v4.w);
    }
    __syncthreads();
#pragma unroll 8
    for (int m = 0; m < 64; ++m) {
      float k0 = Kt[m][ty * 4 + 0], k1 = Kt[m][ty * 4 + 1];
      float k2 = Kt[m][ty * 4 + 2], k3 = Kt[m][ty * 4 + 3];
      float v0 = Vt[m][tx * 4 + 0], v1 = Vt[m][tx * 4 + 1];
      float v2 = Vt[m][tx * 4 + 2], v3 = Vt[m][tx * 4 + 3];
      S[0][0] += k0 * v0; S[0][1] += k0 * v1; S[0][2] += k0 * v2; S[0][3] += k0 * v3;
      S[1][0] += k1 * v0; S[1][1] += k1 * v1; S[1][2] += k1 * v2; S[1][3] += k1 * v3;
      S[2][0] += k2 * v0; S[2][1] += k2 * v1; S[2][2] += k2 * v2; S[2][3] += k2 * v3;
      S[3][0] += k3 * v0; S[3][1] += k3 * v1; S[3][2] += k3 * v2; S[3][3] += k3 * v3;
    }
    __syncthreads();
  }
#pragma unroll
  for (int i = 0; i < 4; ++i)
#pragma unroll
    for (int j = 0; j < 4; ++j) St[ty * 4 + i][tx * 4 + j] = S[i][j];
  __syncthreads();

  for (int nb = 0; nb < 8; ++nb) {
#pragma unroll
    for (int rr = 0; rr < 4; ++rr) {
      int row = rr * 16 + ty;
      ushort4 q4 = *reinterpret_cast<const ushort4*>(Q + base + (size_t)(nb * 64 + row) * D_DIM + tx * 4);
      Kt[row][tx * 4 + 0] = bf2f(q4.x); Kt[row][tx * 4 + 1] = bf2f(q4.y);
      Kt[row][tx * 4 + 2] = bf2f(q4.z); Kt[row][tx * 4 + 3] = bf2f(q4.w);
    }
    __syncthreads();
    float o[4][4] = {};
#pragma unroll 16
    for (int i = 0; i < 64; ++i) {
      float q0 = Kt[ty * 4 + 0][i], q1 = Kt[ty * 4 + 1][i];
      float q2 = Kt[ty * 4 + 2][i], q3 = Kt[ty * 4 + 3][i];
      float s0 = St[i][tx * 4 + 0], s1 = St[i][tx * 4 + 1];
      float s2 = St[i][tx * 4 + 2], s3 = St[i][tx * 4 + 3];
      o[0][0] += q0 * s0; o[0][1] += q0 * s1; o[0][2] += q0 * s2; o[0][3] += q0 * s3;
      o[1][0] += q1 * s0; o[1][1] += q1 * s1; o[1][2] += q1 * s2; o[1][3] += q1 * s3;
      o[2][0] += q2 * s0; o[2][1] += q2 * s1; o[2][2] += q2 * s2; o[2][3] += q2 * s3;
      o[3][0] += q3 * s0; o[3][1] += q3 * s1; o[3][2] += q3 * s2; o[3][3] += q3 * s3;
    }
#pragma unroll
    for (int r = 0; r < 4; ++r) {
      float4 ov;
      ov.x = o[r][0] * 0.125f; ov.y = o[r][1] * 0.125f;
      ov.z = o[r][2] * 0.125f; ov.w = o[r][3] * 0.125f;
      *reinterpret_cast<float4*>(O + base + (size_t)(nb * 64 + ty * 4 + r) * D_DIM + tx * 4) = ov;
    }
    __syncthreads();
  }
}

// ---------------------------------------------------------------------------
// LIF over attention u (exact f32 values, f64 state), writes bf16 spikes.
// ---------------------------------------------------------------------------
__global__ __launch_bounds__(256) void lif_plane(const float* __restrict__ U,
                                                 unsigned short* __restrict__ S) {
  int e = blockIdx.x * 256 + threadIdx.x;
  double v = 0.0;
#pragma unroll
  for (int t = 0; t < T_STEPS; ++t) {
    size_t idx = (size_t)t * (BN * D_DIM) + e;
    double u = (double)U[idx];
    v = v + (u - v) * 0.5;
    float s = (v >= 1.0) ? 1.0f : 0.0f;
    v = (v >= 1.0) ? 0.0 : v;
    S[idx] = f2bf(s);
  }
}

// ---------------------------------------------------------------------------
extern "C" void kernel_launch(void* const* d_in, const int* in_sizes, int n_in,
                              void* d_out, int out_size, void* d_ws, size_t ws_size,
                              hipStream_t stream) {
  const float* x    = (const float*)d_in[0];
  const float* enc  = (const float*)d_in[1];
  const float* Wq_s = (const float*)d_in[2];
  const float* bq_s = (const float*)d_in[3];
  const float* Wk_s = (const float*)d_in[4];
  const float* bk_s = (const float*)d_in[5];
  const float* Wv_s = (const float*)d_in[6];
  const float* bv_s = (const float*)d_in[7];
  const float* Wo_s = (const float*)d_in[8];
  const float* bo_s = (const float*)d_in[9];
  const float* Wq_c = (const float*)d_in[10];
  const float* bq_c = (const float*)d_in[11];
  const float* Wk_c = (const float*)d_in[12];
  const float* bk_c = (const float*)d_in[13];
  const float* Wv_c = (const float*)d_in[14];
  const float* bv_c = (const float*)d_in[15];
  const float* Wo_c = (const float*)d_in[16];
  const float* bo_c = (const float*)d_in[17];
  const float* W1   = (const float*)d_in[18];
  const float* b1   = (const float*)d_in[19];
  const float* W2   = (const float*)d_in[20];
  const float* b2   = (const float*)d_in[21];
  float* out = (float*)d_out;

  // Workspace (48 MB):
  //  0- 8 MB: qs (bf16 [R,D]); later attention spikes as_
  //  8-16 MB: ks;  8-40 MB later h_spk (bf16 [R,F], over ks/vs/u_attn)
  // 16-24 MB: vs
  // 24-40 MB: u_attn (f32 [R,D])
  // 40-48 MB: s1 (bf16 [R,D]) spike-sum of the two attention blocks
  char* pool = (char*)d_ws;
  const size_t MB = 1024 * 1024;
  unsigned short* qs     = (unsigned short*)(pool + 0 * MB);
  unsigned short* ks     = (unsigned short*)(pool + 8 * MB);
  unsigned short* vs     = (unsigned short*)(pool + 16 * MB);
  float*          u_attn = (float*)(pool + 24 * MB);
  unsigned short* as_    = (unsigned short*)(pool + 0 * MB);
  unsigned short* h_spk  = (unsigned short*)(pool + 8 * MB);
  unsigned short* s1     = (unsigned short*)(pool + 40 * MB);

  const unsigned short* NULS = nullptr;
  const float* NULF = nullptr;
  dim3 blk(256);
  dim3 gD(D_DIM / 64, BN / 32);   // (8, 64)
  dim3 gF(F_DIM / 64, BN / 32);   // (32, 64)
  int gLif = (BN * D_DIM) / 256;

  // ---- Block 1: self-attention ----
  gemm_lif<<<gD, blk, 0, stream>>>(x, NULS, Wq_s, bq_s, NULS, NULF, NULS, qs, D_DIM, D_DIM, MODE_SPK, 0);
  gemm_lif<<<gD, blk, 0, stream>>>(x, NULS, Wk_s, bk_s, NULS, NULF, NULS, ks, D_DIM, D_DIM, MODE_SPK, 0);
  gemm_lif<<<gD, blk, 0, stream>>>(x, NULS, Wv_s, bv_s, NULS, NULF, NULS, vs, D_DIM, D_DIM, MODE_SPK, 0);
  attn_k<<<128, blk, 0, stream>>>(qs, ks, vs, u_attn);
  lif_plane<<<gLif, blk, 0, stream>>>(u_attn, as_);
  gemm_lif<<<gD, blk, 0, stream>>>(as_, NULS, Wo_s, bo_s, NULS, NULF, NULS, s1, D_DIM, D_DIM, MODE_SPK, 1);

  // ---- Block 2: cross-attention (A_q = x + s1, exact via dual staging) ----
  gemm_lif<<<gD, blk, 0, stream>>>(x, s1, Wq_c, bq_c, NULS, NULF, NULS, qs, D_DIM, D_DIM, MODE_SPK, 0);
  gemm_lif<<<gD, blk, 0, stream>>>(enc, NULS, Wk_c, bk_c, NULS, NULF, NULS, ks, D_DIM, D_DIM, MODE_SPK, 0);
  gemm_lif<<<gD, blk, 0, stream>>>(enc, NULS, Wv_c, bv_c, NULS, NULF, NULS, vs, D_DIM, D_DIM, MODE_SPK, 0);
  attn_k<<<128, blk, 0, stream>>>(qs, ks, vs, u_attn);
  lif_plane<<<gLif, blk, 0, stream>>>(u_attn, as_);
  gemm_lif<<<gD, blk, 0, stream>>>(as_, NULS, Wo_c, bo_c, s1, NULF, NULS, s1, D_DIM, D_DIM, MODE_SPK_ADD, 1);

  // ---- Block 3: spiking MLP (A = x + s1; final fused residual output) ----
  gemm_lif<<<gF, blk, 0, stream>>>(x, s1, W1, b1, NULS, NULF, NULS, h_spk, F_DIM, D_DIM, MODE_SPK, 0);
  gemm_lif<<<gD, blk, 0, stream>>>(h_spk, NULS, W2, b2, NULS, x, s1, out, D_DIM, F_DIM, MODE_OUT, 1);

  (void)in_sizes; (void)n_in; (void)out_size; (void)ws_size;
}

// Round 4
// 1675.617 us; speedup vs baseline: 1.5983x; 1.5983x over previous
//
#include <hip/hip_runtime.h>
#include <cstddef>

// DecoderLayer: T=4, B=4, N=512, D=512, F=2048, H=8, head_dim=64
// I/O: float32. Spike intermediates: bf16 (exact for {0,1,2}).
// GEMM accumulation + LIF recurrence in f64 (matches np float64 ref; round 3
// proved absmax 0.0 with f64). This round: f64 MFMA (v_mfma_f64_16x16x4_f64)
// replaces the f64 VALU inner loop -- ~3x FLOP rate + VALU freed for staging.
#define T_STEPS 4
#define BN 2048                    /* B*N rows per time plane */
#define N_TOK 512
#define D_DIM 512
#define F_DIM 2048

#define MODE_SPK 0
#define MODE_SPK_ADD 1
#define MODE_OUT 2

typedef double d4 __attribute__((ext_vector_type(4)));

__device__ __forceinline__ float bf2f(unsigned short u) {
  unsigned int x = ((unsigned int)u) << 16;
  float f;
  __builtin_memcpy(&f, &x, 4);
  return f;
}
__device__ __forceinline__ unsigned short f2bf(float f) {
  unsigned int x;
  __builtin_memcpy(&x, &f, 4);
  x += 0x7fffu + ((x >> 16) & 1u);  // round to nearest even
  return (unsigned short)(x >> 16);
}

// ---------------------------------------------------------------------------
// MFMA-f64 fused GEMM + LIF over T.
// Block tile: 64 cols x 64 rows, where tile-row r = t*16 + bn_local
// (16 bn-rows x 4 time planes). u[t] = (A1[t](+A2[t])) @ W + bias in f64 via
// v_mfma_f64_16x16x4_f64; LIF across t in f64; outputs per mode.
// 4 waves: wave w -> (wr=w>>1 row-half, wc=w&1 col-half), each 32x32 = 2x2
// mfma tiles. m-tile mt of wave wr covers t = wr*2 + mt.
// C/D layout (16x16): col = lane&15, row = (lane>>4)*4 + j  => each lane of
// waves 0/1 holds u(t=0),u(t=1) for its 8 (bn,col) pairs; waves 2/3 hold
// t=2,3 and pass them via LDS for the LIF scan.
// Grid: (N/64, BN/16), block 256.
// ---------------------------------------------------------------------------
__global__ __launch_bounds__(256) void gemm_lif(
    const void* __restrict__ A1v,
    const unsigned short* __restrict__ A2,     // nullable bf16 spike-sum
    const float* __restrict__ W,
    const float* __restrict__ bias,
    const unsigned short* Sprev,               // mode 1 (may alias outv)
    const float* __restrict__ Xres,            // mode 2
    const unsigned short* __restrict__ S12,    // mode 2
    void* outv,
    int N, int K, int mode, int a1bf) {
  // LDS: As[16][67] + Bs[16][67] doubles (17.2 KB); epilogue reuses the same
  // space as Ux[16][128] (16 KB) after the final barrier.
  __shared__ double smem[2144];
#define AS(k, r) smem[(size_t)(k) * 67 + (r)]
#define BS(k, n) smem[1072 + (size_t)(k) * 67 + (n)]
#define UX(i, p) smem[(size_t)(i) * 128 + (p)]

  const int tid = threadIdx.x;
  const int lane = tid & 63;
  const int wave = tid >> 6;
  const int wr = wave >> 1, wc = wave & 1;
  const int lm = lane & 15;        // 16-dim index (A rows / B cols / C cols)
  const int kl = lane >> 4;        // k-slice 0..3 within mfma
  const int n0 = blockIdx.x * 64;
  const int bn0 = blockIdx.y * 16;

  // A staging: tile-row r_s = tid>>2 (0..63), k-quad kq_s = (tid&3)*4
  const int r_s = tid >> 2;
  const int kq_s = (tid & 3) * 4;
  const size_t arow = (size_t)((r_s >> 4) * BN + bn0 + (r_s & 15)) * K;
  // B staging: k-row kb_s = tid>>4 (0..15), col-quad nq_s = (tid&15)*4
  const int kb_s = tid >> 4;
  const int nq_s = (tid & 15) * 4;

  d4 acc00 = {0.0, 0.0, 0.0, 0.0};
  d4 acc01 = {0.0, 0.0, 0.0, 0.0};
  d4 acc10 = {0.0, 0.0, 0.0, 0.0};
  d4 acc11 = {0.0, 0.0, 0.0, 0.0};

  for (int k0 = 0; k0 < K; k0 += 16) {
    // ---- stage A (f64, with exact spike add) ----
    {
      double ad[4];
      if (a1bf) {
        ushort4 p = *reinterpret_cast<const ushort4*>(
            (const unsigned short*)A1v + arow + k0 + kq_s);
        ad[0] = (double)bf2f(p.x); ad[1] = (double)bf2f(p.y);
        ad[2] = (double)bf2f(p.z); ad[3] = (double)bf2f(p.w);
      } else {
        float4 p = *reinterpret_cast<const float4*>(
            (const float*)A1v + arow + k0 + kq_s);
        ad[0] = (double)p.x; ad[1] = (double)p.y;
        ad[2] = (double)p.z; ad[3] = (double)p.w;
      }
      if (A2 != nullptr) {
        ushort4 q = *reinterpret_cast<const ushort4*>(A2 + arow + k0 + kq_s);
        ad[0] += (double)bf2f(q.x); ad[1] += (double)bf2f(q.y);
        ad[2] += (double)bf2f(q.z); ad[3] += (double)bf2f(q.w);
      }
      AS(kq_s + 0, r_s) = ad[0];
      AS(kq_s + 1, r_s) = ad[1];
      AS(kq_s + 2, r_s) = ad[2];
      AS(kq_s + 3, r_s) = ad[3];
    }
    // ---- stage B ----
    {
      float4 w4 = *reinterpret_cast<const float4*>(
          W + (size_t)(k0 + kb_s) * N + n0 + nq_s);
      BS(kb_s, nq_s + 0) = (double)w4.x;
      BS(kb_s, nq_s + 1) = (double)w4.y;
      BS(kb_s, nq_s + 2) = (double)w4.z;
      BS(kb_s, nq_s + 3) = (double)w4.w;
    }
    __syncthreads();
#pragma unroll
    for (int kc = 0; kc < 4; ++kc) {
      const int kk = kc * 4 + kl;
      double a0 = AS(kk, wr * 32 + lm);
      double a1 = AS(kk, wr * 32 + 16 + lm);
      double b0 = BS(kk, wc * 32 + lm);
      double b1 = BS(kk, wc * 32 + 16 + lm);
      acc00 = __builtin_amdgcn_mfma_f64_16x16x4f64(a0, b0, acc00, 0, 0, 0);
      acc01 = __builtin_amdgcn_mfma_f64_16x16x4f64(a0, b1, acc01, 0, 0, 0);
      acc10 = __builtin_amdgcn_mfma_f64_16x16x4f64(a1, b0, acc10, 0, 0, 0);
      acc11 = __builtin_amdgcn_mfma_f64_16x16x4f64(a1, b1, acc11, 0, 0, 0);
    }
    __syncthreads();
  }

  // ---- epilogue: waves 2,3 (t=2,3) ship u via LDS; waves 0,1 run LIF ----
  if (wr == 1) {
#pragma unroll
    for (int j = 0; j < 4; ++j) {
      UX(0 + 0 * 4 + j, wc * 64 + lane) = acc00[j];  // mt0 (t=2), nt0
      UX(0 + 1 * 4 + j, wc * 64 + lane) = acc01[j];  // mt0 (t=2), nt1
      UX(8 + 0 * 4 + j, wc * 64 + lane) = acc10[j];  // mt1 (t=3), nt0
      UX(8 + 1 * 4 + j, wc * 64 + lane) = acc11[j];  // mt1 (t=3), nt1
    }
  }
  __syncthreads();
  if (wr == 0) {
    const double bd[2] = {(double)bias[n0 + wc * 32 + lm],
                          (double)bias[n0 + wc * 32 + 16 + lm]};
#pragma unroll
    for (int nt = 0; nt < 2; ++nt) {
      const int col = n0 + wc * 32 + nt * 16 + lm;
      const double bb = bd[nt];
#pragma unroll
      for (int j = 0; j < 4; ++j) {
        const int bn = bn0 + kl * 4 + j;
        double u[4];
        u[0] = (nt ? acc01[j] : acc00[j]) + bb;  // mt0 -> t=0
        u[1] = (nt ? acc11[j] : acc10[j]) + bb;  // mt1 -> t=1
        u[2] = UX(0 + nt * 4 + j, wc * 64 + lane) + bb;  // t=2
        u[3] = UX(8 + nt * 4 + j, wc * 64 + lane) + bb;  // t=3
        double v = 0.0;
#pragma unroll
        for (int t = 0; t < T_STEPS; ++t) {
          v = v + (u[t] - v) * 0.5;
          float s = (v >= 1.0) ? 1.0f : 0.0f;
          v = (v >= 1.0) ? 0.0 : v;
          size_t idx = (size_t)(t * BN + bn) * N + col;
          if (mode == MODE_SPK) {
            ((unsigned short*)outv)[idx] = f2bf(s);
          } else if (mode == MODE_SPK_ADD) {
            ((unsigned short*)outv)[idx] = f2bf(s + bf2f(Sprev[idx]));
          } else {
            ((float*)outv)[idx] =
                (float)((double)Xres[idx] + (double)bf2f(S12[idx]) + (double)s);
          }
        }
      }
    }
  }
#undef AS
#undef BS
#undef UX
}

// ---------------------------------------------------------------------------
// Spiking attention, reassociated: u = 0.125 * q @ (k^T @ v) per (t,b,h).
// Spikes are 0/1 -> exact integer sums (< 2^24) in f32; identical to the
// reference's (q@k^T)@v order. bf16 spikes in, exact f32 u out. Grid 128.
// ---------------------------------------------------------------------------
__global__ __launch_bounds__(256) void attn_k(const unsigned short* __restrict__ Q,
                                              const unsigned short* __restrict__ K,
                                              const unsigned short* __restrict__ V,
                                              float* __restrict__ O) {
  const int blk = blockIdx.x;
  const int h = blk & 7;
  const int tb = blk >> 3;
  const size_t base = (size_t)tb * (N_TOK * D_DIM) + h * 64;
  const int tid = threadIdx.x;
  const int tx = tid & 15, ty = tid >> 4;

  __shared__ float Kt[64][65];
  __shared__ float Vt[64][65];
  __shared__ float St[64][65];

  float S[4][4] = {};
  for (int mc = 0; mc < N_TOK; mc += 64) {
#pragma unroll
    for (int rr = 0; rr < 4; ++rr) {
      int row = rr * 16 + ty;
      ushort4 k4 = *reinterpret_cast<const ushort4*>(K + base + (size_t)(mc + row) * D_DIM + tx * 4);
      ushort4 v4 = *reinterpret_cast<const ushort4*>(V + base + (size_t)(mc + row) * D_DIM + tx * 4);
      Kt[row][tx * 4 + 0] = bf2f(k4.x); Kt[row][tx * 4 + 1] = bf2f(k4.y);
      Kt[row][tx * 4 + 2] = bf2f(k4.z); Kt[row][tx * 4 + 3] = bf2f(k4.w);
      Vt[row][tx * 4 + 0] = bf2f(v4.x); Vt[row][tx * 4 + 1] = bf2f(v4.y);
      Vt[row][tx * 4 + 2] = bf2f(v4.z); Vt[row][tx * 4 + 3] = bf2f(v4.w);
    }
    __syncthreads();
#pragma unroll 8
    for (int m = 0; m < 64; ++m) {
      float k0 = Kt[m][ty * 4 + 0], k1 = Kt[m][ty * 4 + 1];
      float k2 = Kt[m][ty * 4 + 2], k3 = Kt[m][ty * 4 + 3];
      float v0 = Vt[m][tx * 4 + 0], v1 = Vt[m][tx * 4 + 1];
      float v2 = Vt[m][tx * 4 + 2], v3 = Vt[m][tx * 4 + 3];
      S[0][0] += k0 * v0; S[0][1] += k0 * v1; S[0][2] += k0 * v2; S[0][3] += k0 * v3;
      S[1][0] += k1 * v0; S[1][1] += k1 * v1; S[1][2] += k1 * v2; S[1][3] += k1 * v3;
      S[2][0] += k2 * v0; S[2][1] += k2 * v1; S[2][2] += k2 * v2; S[2][3] += k2 * v3;
      S[3][0] += k3 * v0; S[3][1] += k3 * v1; S[3][2] += k3 * v2; S[3][3] += k3 * v3;
    }
    __syncthreads();
  }
#pragma unroll
  for (int i = 0; i < 4; ++i)
#pragma unroll
    for (int j = 0; j < 4; ++j) St[ty * 4 + i][tx * 4 + j] = S[i][j];
  __syncthreads();

  for (int nb = 0; nb < 8; ++nb) {
#pragma unroll
    for (int rr = 0; rr < 4; ++rr) {
      int row = rr * 16 + ty;
      ushort4 q4 = *reinterpret_cast<const ushort4*>(Q + base + (size_t)(nb * 64 + row) * D_DIM + tx * 4);
      Kt[row][tx * 4 + 0] = bf2f(q4.x); Kt[row][tx * 4 + 1] = bf2f(q4.y);
      Kt[row][tx * 4 + 2] = bf2f(q4.z); Kt[row][tx * 4 + 3] = bf2f(q4.w);
    }
    __syncthreads();
    float o[4][4] = {};
#pragma unroll 16
    for (int i = 0; i < 64; ++i) {
      float q0 = Kt[ty * 4 + 0][i], q1 = Kt[ty * 4 + 1][i];
      float q2 = Kt[ty * 4 + 2][i], q3 = Kt[ty * 4 + 3][i];
      float s0 = St[i][tx * 4 + 0], s1 = St[i][tx * 4 + 1];
      float s2 = St[i][tx * 4 + 2], s3 = St[i][tx * 4 + 3];
      o[0][0] += q0 * s0; o[0][1] += q0 * s1; o[0][2] += q0 * s2; o[0][3] += q0 * s3;
      o[1][0] += q1 * s0; o[1][1] += q1 * s1; o[1][2] += q1 * s2; o[1][3] += q1 * s3;
      o[2][0] += q2 * s0; o[2][1] += q2 * s1; o[2][2] += q2 * s2; o[2][3] += q2 * s3;
      o[3][0] += q3 * s0; o[3][1] += q3 * s1; o[3][2] += q3 * s2; o[3][3] += q3 * s3;
    }
#pragma unroll
    for (int r = 0; r < 4; ++r) {
      float4 ov;
      ov.x = o[r][0] * 0.125f; ov.y = o[r][1] * 0.125f;
      ov.z = o[r][2] * 0.125f; ov.w = o[r][3] * 0.125f;
      *reinterpret_cast<float4*>(O + base + (size_t)(nb * 64 + ty * 4 + r) * D_DIM + tx * 4) = ov;
    }
    __syncthreads();
  }
}

// ---------------------------------------------------------------------------
// LIF over attention u (exact f32 values, f64 state), writes bf16 spikes.
// ---------------------------------------------------------------------------
__global__ __launch_bounds__(256) void lif_plane(const float* __restrict__ U,
                                                 unsigned short* __restrict__ S) {
  int e = blockIdx.x * 256 + threadIdx.x;
  double v = 0.0;
#pragma unroll
  for (int t = 0; t < T_STEPS; ++t) {
    size_t idx = (size_t)t * (BN * D_DIM) + e;
    double u = (double)U[idx];
    v = v + (u - v) * 0.5;
    float s = (v >= 1.0) ? 1.0f : 0.0f;
    v = (v >= 1.0) ? 0.0 : v;
    S[idx] = f2bf(s);
  }
}

// ---------------------------------------------------------------------------
extern "C" void kernel_launch(void* const* d_in, const int* in_sizes, int n_in,
                              void* d_out, int out_size, void* d_ws, size_t ws_size,
                              hipStream_t stream) {
  const float* x    = (const float*)d_in[0];
  const float* enc  = (const float*)d_in[1];
  const float* Wq_s = (const float*)d_in[2];
  const float* bq_s = (const float*)d_in[3];
  const float* Wk_s = (const float*)d_in[4];
  const float* bk_s = (const float*)d_in[5];
  const float* Wv_s = (const float*)d_in[6];
  const float* bv_s = (const float*)d_in[7];
  const float* Wo_s = (const float*)d_in[8];
  const float* bo_s = (const float*)d_in[9];
  const float* Wq_c = (const float*)d_in[10];
  const float* bq_c = (const float*)d_in[11];
  const float* Wk_c = (const float*)d_in[12];
  const float* bk_c = (const float*)d_in[13];
  const float* Wv_c = (const float*)d_in[14];
  const float* bv_c = (const float*)d_in[15];
  const float* Wo_c = (const float*)d_in[16];
  const float* bo_c = (const float*)d_in[17];
  const float* W1   = (const float*)d_in[18];
  const float* b1   = (const float*)d_in[19];
  const float* W2   = (const float*)d_in[20];
  const float* b2   = (const float*)d_in[21];
  float* out = (float*)d_out;

  // Workspace (48 MB):
  //  0- 8 MB: qs (bf16 [R,D]); later attention spikes as_
  //  8-16 MB: ks;  8-40 MB later h_spk (bf16 [R,F], over ks/vs/u_attn)
  // 16-24 MB: vs
  // 24-40 MB: u_attn (f32 [R,D])
  // 40-48 MB: s1 (bf16 [R,D]) spike-sum of the two attention blocks
  char* pool = (char*)d_ws;
  const size_t MB = 1024 * 1024;
  unsigned short* qs     = (unsigned short*)(pool + 0 * MB);
  unsigned short* ks     = (unsigned short*)(pool + 8 * MB);
  unsigned short* vs     = (unsigned short*)(pool + 16 * MB);
  float*          u_attn = (float*)(pool + 24 * MB);
  unsigned short* as_    = (unsigned short*)(pool + 0 * MB);
  unsigned short* h_spk  = (unsigned short*)(pool + 8 * MB);
  unsigned short* s1     = (unsigned short*)(pool + 40 * MB);

  const unsigned short* NULS = nullptr;
  const float* NULF = nullptr;
  dim3 blk(256);
  dim3 gD(D_DIM / 64, BN / 16);   // (8, 128)
  dim3 gF(F_DIM / 64, BN / 16);   // (32, 128)
  int gLif = (BN * D_DIM) / 256;

  // ---- Block 1: self-attention ----
  gemm_lif<<<gD, blk, 0, stream>>>(x, NULS, Wq_s, bq_s, NULS, NULF, NULS, qs, D_DIM, D_DIM, MODE_SPK, 0);
  gemm_lif<<<gD, blk, 0, stream>>>(x, NULS, Wk_s, bk_s, NULS, NULF, NULS, ks, D_DIM, D_DIM, MODE_SPK, 0);
  gemm_lif<<<gD, blk, 0, stream>>>(x, NULS, Wv_s, bv_s, NULS, NULF, NULS, vs, D_DIM, D_DIM, MODE_SPK, 0);
  attn_k<<<128, blk, 0, stream>>>(qs, ks, vs, u_attn);
  lif_plane<<<gLif, blk, 0, stream>>>(u_attn, as_);
  gemm_lif<<<gD, blk, 0, stream>>>(as_, NULS, Wo_s, bo_s, NULS, NULF, NULS, s1, D_DIM, D_DIM, MODE_SPK, 1);

  // ---- Block 2: cross-attention (A_q = x + s1, exact via dual staging) ----
  gemm_lif<<<gD, blk, 0, stream>>>(x, s1, Wq_c, bq_c, NULS, NULF, NULS, qs, D_DIM, D_DIM, MODE_SPK, 0);
  gemm_lif<<<gD, blk, 0, stream>>>(enc, NULS, Wk_c, bk_c, NULS, NULF, NULS, ks, D_DIM, D_DIM, MODE_SPK, 0);
  gemm_lif<<<gD, blk, 0, stream>>>(enc, NULS, Wv_c, bv_c, NULS, NULF, NULS, vs, D_DIM, D_DIM, MODE_SPK, 0);
  attn_k<<<128, blk, 0, stream>>>(qs, ks, vs, u_attn);
  lif_plane<<<gLif, blk, 0, stream>>>(u_attn, as_);
  gemm_lif<<<gD, blk, 0, stream>>>(as_, NULS, Wo_c, bo_c, s1, NULF, NULS, s1, D_DIM, D_DIM, MODE_SPK_ADD, 1);

  // ---- Block 3: spiking MLP (A = x + s1; final fused residual output) ----
  gemm_lif<<<gF, blk, 0, stream>>>(x, s1, W1, b1, NULS, NULF, NULS, h_spk, F_DIM, D_DIM, MODE_SPK, 0);
  gemm_lif<<<gD, blk, 0, stream>>>(h_spk, NULS, W2, b2, NULS, x, s1, out, D_DIM, F_DIM, MODE_OUT, 1);

  (void)in_sizes; (void)n_in; (void)out_size; (void)ws_size;
}